// Round 1
// baseline (347.786 us; speedup 1.0000x reference)
//
#include <hip/hip_runtime.h>
#include <stdint.h>

#define B_  4
#define NQ_ 2048
#define NP_ 8192
#define D_  256
#define F_  40
#define K_  16

// ---------------- Kernel 1: hash codes -------------------------------------
// One thread per vector. 40 fp32 dot products of length 256; sign bits packed
// into a 40-bit code. proj accesses are wave-uniform -> scalar loads.
__global__ __launch_bounds__(256) void hash_kernel(
    const float* __restrict__ qp, const float* __restrict__ pp,
    const float* __restrict__ proj, uint64_t* __restrict__ qcodes,
    uint64_t* __restrict__ pcodes) {
  int tid = blockIdx.x * 256 + threadIdx.x;
  const float* src;
  uint64_t* dst;
  if (tid < B_ * NQ_) {
    src = qp + (size_t)tid * D_;
    dst = qcodes + tid;
  } else {
    int t = tid - B_ * NQ_;
    src = pp + (size_t)t * D_;
    dst = pcodes + t;
  }
  float acc[F_];
#pragma unroll
  for (int f = 0; f < F_; ++f) acc[f] = 0.0f;
  const float4* src4 = (const float4*)src;
  for (int c = 0; c < 8; ++c) {  // 8 chunks of 32 dims
    float x[32];
#pragma unroll
    for (int u = 0; u < 8; ++u) {
      float4 v = src4[c * 8 + u];
      x[u * 4 + 0] = v.x; x[u * 4 + 1] = v.y;
      x[u * 4 + 2] = v.z; x[u * 4 + 3] = v.w;
    }
#pragma unroll
    for (int f = 0; f < F_; ++f) {
      const float* pr = proj + f * D_ + c * 32;
      float a = acc[f];
#pragma unroll
      for (int dd = 0; dd < 32; ++dd) a = fmaf(x[dd], pr[dd], a);
      acc[f] = a;
    }
  }
  uint64_t code = 0;
#pragma unroll
  for (int f = 0; f < F_; ++f)
    if (acc[f] > 0.0f) code |= (1ull << f);
  *dst = code;
}

// ---------------- Kernel 2: exact top-16 by (dist, index) -------------------
// One wave per query; 4 waves/block share a 64KB LDS tile of the batch's
// point codes. Distances are 6-bit (<=40): two packed-byte-counter passes
// find the exact k-th threshold, a third pass collects keys in index order.
__global__ __launch_bounds__(256) void select_kernel(
    const uint64_t* __restrict__ qcodes, const uint64_t* __restrict__ pcodes,
    float* __restrict__ outIdx, float* __restrict__ outDist) {
  __shared__ uint64_t ldsP[NP_];       // 64 KB
  __shared__ unsigned keybuf[4][K_];

  int bb = blockIdx.x >> 9;  // 512 blocks per batch (2048 queries / 4 per block)
  const uint64_t* pb = pcodes + (size_t)bb * NP_;
  for (int i = threadIdx.x; i < NP_; i += 256) ldsP[i] = pb[i];
  __syncthreads();

  int w = threadIdx.x >> 6, lane = threadIdx.x & 63;
  int qg = blockIdx.x * 4 + w;
  uint64_t qc = qcodes[qg];
  const uint64_t M = 0x00FF00FF00FF00FFull;

  // ---- Pass 1: coarse histogram of dist>>3 (6 buckets, packed bytes) ----
  uint64_t c8 = 0;
#pragma unroll 8
  for (int j = 0; j < 128; ++j) {
    uint64_t pc = ldsP[j * 64 + lane];
    int d = __popcll(qc ^ pc);
    c8 += 1ull << (d & 56);            // (d>>3)*8 == d & 56 for d < 64
  }
  uint64_t e = c8 & M, o = (c8 >> 8) & M;  // widen bytes -> 16-bit fields
#pragma unroll
  for (int s = 1; s < 64; s <<= 1) { e += __shfl_xor(e, s); o += __shfl_xor(o, s); }
  int Bb = 0; unsigned nbefore = 0, cum = 0; bool found = false;
#pragma unroll
  for (int k2 = 0; k2 < 6; ++k2) {
    unsigned c = (unsigned)(((k2 & 1) ? o : e) >> ((k2 >> 1) * 16)) & 0xFFFFu;
    if (!found && cum + c >= K_) { Bb = k2; nbefore = cum; found = true; }
    cum += c;
  }

  // ---- Pass 2: fine histogram of the 8 dists inside bucket Bb ----
  int base = Bb * 8;
  uint64_t cf = 0;
#pragma unroll 8
  for (int j = 0; j < 128; ++j) {
    uint64_t pc = ldsP[j * 64 + lane];
    int d = __popcll(qc ^ pc);
    unsigned rel = (unsigned)(d - base);
    if (rel < 8u) cf += 1ull << (rel << 3);
  }
  e = cf & M; o = (cf >> 8) & M;
#pragma unroll
  for (int s = 1; s < 64; s <<= 1) { e += __shfl_xor(e, s); o += __shfl_xor(o, s); }
  int t = 0; unsigned n_lt = 0; cum = nbefore; found = false;
#pragma unroll
  for (int r = 0; r < 8; ++r) {
    unsigned c = (unsigned)(((r & 1) ? o : e) >> ((r >> 1) * 16)) & 0xFFFFu;
    if (!found && cum + c >= K_) { t = base + r; n_lt = cum; found = true; }
    cum += c;
  }
  unsigned r_need = K_ - n_lt;   // how many dist==t entries to take (lowest idx)

  // ---- Pass 3: collect keys in index order ----
  unsigned cl = 0, ce = 0;
  uint64_t lmask = (1ull << lane) - 1;
#pragma unroll 2
  for (int j = 0; j < 128; ++j) {
    int p = j * 64 + lane;
    int d = __popcll(qc ^ ldsP[p]);
    bool blt = (d < t), beq = (d == t);
    uint64_t mlt = __ballot(blt), meq = __ballot(beq);
    if (blt)
      keybuf[w][cl + (unsigned)__popcll(mlt & lmask)] =
          ((unsigned)d << 13) | (unsigned)p;
    if (beq) {
      unsigned pos = ce + (unsigned)__popcll(meq & lmask);
      if (pos < r_need)
        keybuf[w][n_lt + pos] = ((unsigned)d << 13) | (unsigned)p;
    }
    cl += (unsigned)__popcll(mlt);
    ce += (unsigned)__popcll(meq);
  }
  __syncthreads();

  // ---- rank-sort the 16 keys (distinct: idx embedded) and emit ----
  if (lane < K_) {
    unsigned my = keybuf[w][lane];
    int rank = 0;
#pragma unroll
    for (int jj = 0; jj < K_; ++jj) rank += (keybuf[w][jj] < my) ? 1 : 0;
    int off = qg * K_ + rank;
    outIdx[off]  = (float)(my & 8191u);   // index
    outDist[off] = (float)(my >> 13);     // distance
  }
}

extern "C" void kernel_launch(void* const* d_in, const int* in_sizes, int n_in,
                              void* d_out, int out_size, void* d_ws, size_t ws_size,
                              hipStream_t stream) {
  const float* qp   = (const float*)d_in[0];
  const float* pp   = (const float*)d_in[1];
  const float* proj = (const float*)d_in[2];
  // d_in[3] is k (always 16; out_size == B*NQ*16*2 confirms) — hardcoded.

  uint64_t* pcodes = (uint64_t*)d_ws;            // B*NP u64
  uint64_t* qcodes = pcodes + (size_t)B_ * NP_;  // B*NQ u64

  float* outIdx  = (float*)d_out;                    // B*NQ*K indices (as float)
  float* outDist = outIdx + (size_t)B_ * NQ_ * K_;   // B*NQ*K distances

  int total_vecs = B_ * (NQ_ + NP_);                 // 40960
  hash_kernel<<<total_vecs / 256, 256, 0, stream>>>(qp, pp, proj, qcodes, pcodes);
  select_kernel<<<B_ * NQ_ / 4, 256, 0, stream>>>(qcodes, pcodes, outIdx, outDist);
}

// Round 2
// 172.754 us; speedup vs baseline: 2.0132x; 2.0132x over previous
//
#include <hip/hip_runtime.h>
#include <stdint.h>

#define B_  4
#define NQ_ 2048
#define NP_ 8192
#define D_  256
#define F_  40
#define K_  16

// ---------------- Kernel 1: hash codes -------------------------------------
// Block = 256 threads handles 64 vectors. Stage 64x256 fp32 tile in LDS
// (stride 257 -> 2-way bank access = free), coalesced dword staging loads.
// Wave w computes features [10w, 10w+10) for vector = lane; proj base forced
// scalar via readfirstlane so proj reads become s_load (wave-uniform).
// Accumulation order d=0..255 sequential == round-1 order (signs matched np).
__global__ __launch_bounds__(256) void hash_kernel(
    const float* __restrict__ qp, const float* __restrict__ pp,
    const float* __restrict__ proj, uint64_t* __restrict__ qcodes,
    uint64_t* __restrict__ pcodes) {
  __shared__ float tile[64 * 257];
  int t = threadIdx.x;
  int v0 = blockIdx.x * 64;  // first vector in concat [queries; points] space
  bool isQ = v0 < B_ * NQ_;
  const float* src =
      isQ ? (qp + (size_t)v0 * D_) : (pp + (size_t)(v0 - B_ * NQ_) * D_);

  // Stage: iter i loads row i; thread t covers column t (coalesced dwords).
#pragma unroll 8
  for (int i = 0; i < 64; ++i) tile[i * 257 + t] = src[i * 256 + t];
  __syncthreads();

  int lane = t & 63, w = t >> 6;
  int fbase = __builtin_amdgcn_readfirstlane(w * 10);
  const float* pj = proj + (size_t)fbase * 256;

  float acc[10];
#pragma unroll
  for (int f = 0; f < 10; ++f) acc[f] = 0.0f;
#pragma unroll 4
  for (int d = 0; d < 256; ++d) {
    float x = tile[lane * 257 + d];  // bank (lane+d)%32 -> 2-way, free
#pragma unroll
    for (int f = 0; f < 10; ++f) acc[f] = fmaf(x, pj[f * 256 + d], acc[f]);
  }
  unsigned bits = 0;
#pragma unroll
  for (int f = 0; f < 10; ++f)
    if (acc[f] > 0.0f) bits |= 1u << f;

  // Combine the 4 waves' 10-bit chunks per vector (reuse tile LDS).
  __syncthreads();
  unsigned short* cb = (unsigned short*)tile;
  cb[lane * 4 + w] = (unsigned short)bits;
  __syncthreads();
  if (w == 0) {
    uint64_t code = (uint64_t)cb[lane * 4 + 0] |
                    ((uint64_t)cb[lane * 4 + 1] << 10) |
                    ((uint64_t)cb[lane * 4 + 2] << 20) |
                    ((uint64_t)cb[lane * 4 + 3] << 30);
    int gv = v0 + lane;
    if (isQ) qcodes[gv] = code;
    else pcodes[gv - B_ * NQ_] = code;
  }
}

// ---------------- Kernel 2: exact top-16 by (dist, index) -------------------
// 1024-thread block = 16 query-waves sharing one 64KB code tile ->
// 2 blocks/CU = 32 waves/CU (full occupancy). Exact 3-pass selection:
// coarse packed-byte histogram, fine histogram, ordered collection.
__global__ __launch_bounds__(1024) void select_kernel(
    const uint64_t* __restrict__ qcodes, const uint64_t* __restrict__ pcodes,
    float* __restrict__ outIdx, float* __restrict__ outDist) {
  __shared__ ulonglong2 ldsP2[NP_ / 2];  // 64 KB
  __shared__ unsigned keybuf[16][K_];
  uint64_t* ldsP = (uint64_t*)ldsP2;

  int tid = threadIdx.x;
  int bb = blockIdx.x >> 7;  // 128 blocks per batch
  const uint64_t* pb = pcodes + (size_t)bb * NP_;
  for (int i = tid; i < NP_; i += 1024) ldsP[i] = pb[i];
  __syncthreads();

  int w = tid >> 6, lane = tid & 63;
  int qg = blockIdx.x * 16 + w;  // global query id
  uint64_t qc = qcodes[qg];
  const uint64_t M = 0x00FF00FF00FF00FFull;

  // ---- Pass 1: coarse histogram of dist>>3 (6 byte-buckets), point pairs --
  uint64_t c8 = 0;
#pragma unroll 4
  for (int j = 0; j < 64; ++j) {
    ulonglong2 pc = ldsP2[j * 64 + lane];
    int d0 = __popcll(qc ^ pc.x);
    int d1 = __popcll(qc ^ pc.y);
    c8 += (1ull << (d0 & 56)) + (1ull << (d1 & 56));  // (d>>3)*8 == d&56
  }
  uint64_t e = c8 & M, o = (c8 >> 8) & M;
#pragma unroll
  for (int s = 1; s < 64; s <<= 1) { e += __shfl_xor(e, s); o += __shfl_xor(o, s); }
  int Bb = 0; unsigned nbefore = 0, cum = 0; bool found = false;
#pragma unroll
  for (int k2 = 0; k2 < 6; ++k2) {
    unsigned c = (unsigned)(((k2 & 1) ? o : e) >> ((k2 >> 1) * 16)) & 0xFFFFu;
    if (!found && cum + c >= K_) { Bb = k2; nbefore = cum; found = true; }
    cum += c;
  }

  // ---- Pass 2: fine histogram of the 8 dists inside bucket Bb ----
  int base = Bb * 8;
  uint64_t cf = 0;
#pragma unroll 4
  for (int j = 0; j < 64; ++j) {
    ulonglong2 pc = ldsP2[j * 64 + lane];
    unsigned r0 = (unsigned)(__popcll(qc ^ pc.x) - base);
    unsigned r1 = (unsigned)(__popcll(qc ^ pc.y) - base);
    if (r0 < 8u) cf += 1ull << (r0 << 3);
    if (r1 < 8u) cf += 1ull << (r1 << 3);
  }
  e = cf & M; o = (cf >> 8) & M;
#pragma unroll
  for (int s = 1; s < 64; s <<= 1) { e += __shfl_xor(e, s); o += __shfl_xor(o, s); }
  int t = 0; unsigned n_lt = 0; cum = nbefore; found = false;
#pragma unroll
  for (int r = 0; r < 8; ++r) {
    unsigned c = (unsigned)(((r & 1) ? o : e) >> ((r >> 1) * 16)) & 0xFFFFu;
    if (!found && cum + c >= K_) { t = base + r; n_lt = cum; found = true; }
    cum += c;
  }
  unsigned r_need = K_ - n_lt;  // dist==t entries to take (lowest index)

  // ---- Pass 3: collect keys in index order; skip empty iterations ----
  unsigned cl = 0, ce = 0;
  uint64_t lmask = (1ull << lane) - 1;
  for (int j = 0; j < 128; ++j) {
    int p = j * 64 + lane;
    int d = __popcll(qc ^ ldsP[p]);
    if (__any(d <= t)) {
      bool blt = (d < t), beq = (d == t);
      uint64_t mlt = __ballot(blt), meq = __ballot(beq);
      if (blt)
        keybuf[w][cl + (unsigned)__popcll(mlt & lmask)] =
            ((unsigned)d << 13) | (unsigned)p;
      if (beq) {
        unsigned pos = ce + (unsigned)__popcll(meq & lmask);
        if (pos < r_need)
          keybuf[w][n_lt + pos] = ((unsigned)d << 13) | (unsigned)p;
      }
      cl += (unsigned)__popcll(mlt);
      ce += (unsigned)__popcll(meq);
    }
  }
  __syncthreads();

  // ---- rank-sort the 16 keys (distinct: idx embedded) and emit ----
  if (lane < K_) {
    unsigned my = keybuf[w][lane];
    int rank = 0;
#pragma unroll
    for (int jj = 0; jj < K_; ++jj) rank += (keybuf[w][jj] < my) ? 1 : 0;
    int off = qg * K_ + rank;
    outIdx[off]  = (float)(my & 8191u);  // index
    outDist[off] = (float)(my >> 13);    // distance
  }
}

extern "C" void kernel_launch(void* const* d_in, const int* in_sizes, int n_in,
                              void* d_out, int out_size, void* d_ws, size_t ws_size,
                              hipStream_t stream) {
  const float* qp   = (const float*)d_in[0];
  const float* pp   = (const float*)d_in[1];
  const float* proj = (const float*)d_in[2];
  // d_in[3] is k (always 16) — hardcoded.

  uint64_t* pcodes = (uint64_t*)d_ws;            // B*NP u64
  uint64_t* qcodes = pcodes + (size_t)B_ * NP_;  // B*NQ u64

  float* outIdx  = (float*)d_out;                   // B*NQ*K indices (as float)
  float* outDist = outIdx + (size_t)B_ * NQ_ * K_;  // B*NQ*K distances

  int total_vecs = B_ * (NQ_ + NP_);  // 40960
  hash_kernel<<<total_vecs / 64, 256, 0, stream>>>(qp, pp, proj, qcodes, pcodes);
  select_kernel<<<B_ * NQ_ / 16, 1024, 0, stream>>>(qcodes, pcodes, outIdx, outDist);
}